// Round 6
// baseline (687.190 us; speedup 1.0000x reference)
//
#include <hip/hip_runtime.h>

#define F 96
#define SCAN_B 1024
#define CHUNKS 8
#define CW 12        // logical chunk width (F / CHUNKS)

// Wt[c][k] stored XOR-swizzled so column-of-W float4 reads spread across banks.
#define WT_IDX(c, k) ((c) * 96 + (((k) ^ (((c) & 7) << 2))))

// ================= CSR build =================

__global__ void k_zero_i(int* __restrict__ p, int n) {
    int i = blockIdx.x * blockDim.x + threadIdx.x;
    if (i < n) p[i] = 0;
}

__global__ void k_hist(const int* __restrict__ dst, int* __restrict__ hist, int E) {
    int e = blockIdx.x * blockDim.x + threadIdx.x;
    if (e < E) atomicAdd(&hist[dst[e]], 1);
}

__global__ void k_dinv(const int* __restrict__ hist, float* __restrict__ dinv, int N) {
    int i = blockIdx.x * blockDim.x + threadIdx.x;
    if (i < N) dinv[i] = rsqrtf((float)hist[i] + 1.0f);  // +1 self-loop
}

__global__ __launch_bounds__(SCAN_B) void k_scan1(const int* __restrict__ hist,
                                                  int* __restrict__ incl,
                                                  int* __restrict__ bsum, int N) {
    __shared__ int s[SCAN_B];
    int i = blockIdx.x * SCAN_B + threadIdx.x;
    int v = (i < N) ? hist[i] : 0;
    s[threadIdx.x] = v;
    __syncthreads();
    for (int off = 1; off < SCAN_B; off <<= 1) {
        int add = (threadIdx.x >= off) ? s[threadIdx.x - off] : 0;
        __syncthreads();
        s[threadIdx.x] += add;
        __syncthreads();
    }
    if (i < N) incl[i] = s[threadIdx.x];
    if (threadIdx.x == SCAN_B - 1) bsum[blockIdx.x] = s[SCAN_B - 1];
}

__global__ __launch_bounds__(SCAN_B) void k_scan2(int* __restrict__ bsum, int nb) {
    __shared__ int s[SCAN_B];
    int v = (threadIdx.x < nb) ? bsum[threadIdx.x] : 0;
    s[threadIdx.x] = v;
    __syncthreads();
    for (int off = 1; off < SCAN_B; off <<= 1) {
        int add = (threadIdx.x >= off) ? s[threadIdx.x - off] : 0;
        __syncthreads();
        s[threadIdx.x] += add;
        __syncthreads();
    }
    if (threadIdx.x < nb) bsum[threadIdx.x] = s[threadIdx.x] - v;  // exclusive
}

__global__ void k_scan3(const int* __restrict__ incl, const int* __restrict__ hist,
                        const int* __restrict__ bsum, int* __restrict__ row_ptr,
                        int* __restrict__ cursor, int N, int E) {
    int i = blockIdx.x * blockDim.x + threadIdx.x;
    if (i < N) {
        int start = incl[i] - hist[i] + bsum[i / SCAN_B];
        row_ptr[i] = start;
        cursor[i] = start;
    }
    if (i == 0) row_ptr[N] = E;
}

__global__ void k_place(const int* __restrict__ src, const int* __restrict__ dst,
                        int* __restrict__ cursor, int* __restrict__ csr_src, int E) {
    int e = blockIdx.x * blockDim.x + threadIdx.x;
    if (e >= E) return;
    int pos = atomicAdd(&cursor[dst[e]], 1);
    csr_src[pos] = src[e];
}

// ================= dense =================
// COUT_SCALED=true: H' = dinv[row] * ((relu?)(X) @ W), written chunk-major
// [8][N][strideA] with pad slots (>=CW) zeroed. false: plain row-major H.

template <bool RELU_IN, bool CHIN_CHUNK, bool COUT_SCALED>
__global__ __launch_bounds__(256) void k_dense(const float* __restrict__ X,
                                               const float* __restrict__ W,
                                               float* __restrict__ H,
                                               const float* __restrict__ dinv,
                                               int N, int strideA) {
    __shared__ float Wt[96 * 96];
    __shared__ float XsOs[64][100];
    int t = threadIdx.x;
    const size_t NCin = (size_t)N * CW;
    const size_t NCout = (size_t)N * strideA;

    for (int i = t; i < F * F; i += 256) {
        int k = i / F, c = i % F;
        Wt[WT_IDX(c, k)] = W[i];
    }
    int row0 = blockIdx.x * 64;

    // ---- stage input tile ----
    if (CHIN_CHUNK) {
        for (int q = t; q < 1536; q += 256) {
            int f = q / 192, rem = q % 192;
            int node = rem / 3, o = (rem % 3) * 4;
            int gr = row0 + node;
            float4 v = make_float4(0.f, 0.f, 0.f, 0.f);
            if (gr < N) {
                v = *reinterpret_cast<const float4*>(X + (size_t)f * NCin + (size_t)gr * CW + o);
                if (RELU_IN) {
                    v.x = fmaxf(v.x, 0.f); v.y = fmaxf(v.y, 0.f);
                    v.z = fmaxf(v.z, 0.f); v.w = fmaxf(v.w, 0.f);
                }
            }
            *reinterpret_cast<float4*>(&XsOs[node][f * CW + o]) = v;
        }
    } else {
        for (int q = t; q < 1536; q += 256) {
            int node = q / 24, o = (q % 24) * 4;
            int gr = row0 + node;
            float4 v = make_float4(0.f, 0.f, 0.f, 0.f);
            if (gr < N) {
                v = *reinterpret_cast<const float4*>(X + (size_t)gr * F + o);
                if (RELU_IN) {
                    v.x = fmaxf(v.x, 0.f); v.y = fmaxf(v.y, 0.f);
                    v.z = fmaxf(v.z, 0.f); v.w = fmaxf(v.w, 0.f);
                }
            }
            *reinterpret_cast<float4*>(&XsOs[node][o]) = v;
        }
    }
    __syncthreads();

    // ---- compute ----
    int c2 = t & 31;
    int rg = t >> 5;
    float acc[8][3];
#pragma unroll
    for (int j = 0; j < 8; ++j) { acc[j][0] = 0.f; acc[j][1] = 0.f; acc[j][2] = 0.f; }

    for (int k4 = 0; k4 < F; k4 += 4) {
        float4 w0 = *reinterpret_cast<const float4*>(&Wt[WT_IDX(c2, k4)]);
        float4 w1 = *reinterpret_cast<const float4*>(&Wt[WT_IDX(c2 + 32, k4)]);
        float4 w2 = *reinterpret_cast<const float4*>(&Wt[WT_IDX(c2 + 64, k4)]);
#pragma unroll
        for (int j = 0; j < 8; ++j) {
            float4 xv = *reinterpret_cast<const float4*>(&XsOs[rg + 8 * j][k4]);
            acc[j][0] = fmaf(xv.x, w0.x, acc[j][0]);
            acc[j][1] = fmaf(xv.x, w1.x, acc[j][1]);
            acc[j][2] = fmaf(xv.x, w2.x, acc[j][2]);
            acc[j][0] = fmaf(xv.y, w0.y, acc[j][0]);
            acc[j][1] = fmaf(xv.y, w1.y, acc[j][1]);
            acc[j][2] = fmaf(xv.y, w2.y, acc[j][2]);
            acc[j][0] = fmaf(xv.z, w0.z, acc[j][0]);
            acc[j][1] = fmaf(xv.z, w1.z, acc[j][1]);
            acc[j][2] = fmaf(xv.z, w2.z, acc[j][2]);
            acc[j][0] = fmaf(xv.w, w0.w, acc[j][0]);
            acc[j][1] = fmaf(xv.w, w1.w, acc[j][1]);
            acc[j][2] = fmaf(xv.w, w2.w, acc[j][2]);
        }
    }
    __syncthreads();  // all k-loop reads done before overwriting XsOs

    // ---- stage output tile to LDS (scaled by dinv if COUT_SCALED) ----
#pragma unroll
    for (int j = 0; j < 8; ++j) {
        float dd = 1.f;
        if (COUT_SCALED) {
            int gr = row0 + rg + 8 * j;
            dd = (gr < N) ? dinv[gr] : 0.f;
        }
        XsOs[rg + 8 * j][c2]      = acc[j][0] * dd;
        XsOs[rg + 8 * j][c2 + 32] = acc[j][1] * dd;
        XsOs[rg + 8 * j][c2 + 64] = acc[j][2] * dd;
    }
    __syncthreads();

    // ---- coalesced store ----
    if (COUT_SCALED) {
        int nfq = strideA >> 2;  // 3 or 4 float4 per (chunk,node)
        for (int q = t; q < 512 * nfq; q += 256) {
            int ch = q / (64 * nfq);
            int rem = q % (64 * nfq);
            int node = rem / nfq;
            int o4 = (rem % nfq) * 4;
            int gr = row0 + node;
            if (gr < N) {
                float4 v = make_float4(0.f, 0.f, 0.f, 0.f);
                if (o4 < CW) v = *reinterpret_cast<const float4*>(&XsOs[node][ch * CW + o4]);
                *reinterpret_cast<float4*>(H + (size_t)ch * NCout + (size_t)gr * strideA + o4) = v;
            }
        }
    } else {
        for (int q = t; q < 1536; q += 256) {
            int node = q / 24, o = (q % 24) * 4;
            int gr = row0 + node;
            if (gr < N) {
                *reinterpret_cast<float4*>(H + (size_t)gr * F + o) =
                    *reinterpret_cast<const float4*>(&XsOs[node][o]);
            }
        }
    }
}

// ================= gather (chunk x XCD, one node per wave) =================
// chunk = blockIdx&7 (XCD pin). Wave = 4 edge-slots x 16 lanes; lane=es*16+f.
// O[d] = dinv[d] * (sum_e H'[src_e] + H'[d]) + b   (H' prescaled by dinv)

template <bool OUT_ROW>
__global__ __launch_bounds__(256) void k_gather(const float* __restrict__ Hc,
                                                const int* __restrict__ csr_src,
                                                const int* __restrict__ row_ptr,
                                                const float* __restrict__ dinv,
                                                const float* __restrict__ bias,
                                                float* __restrict__ O, int N, int strideA) {
    const int chunk = blockIdx.x & (CHUNKS - 1);
    const int node = (blockIdx.x >> 3) * 4 + (threadIdx.x >> 6);
    if (node >= N) return;
    const int lane = threadIdx.x & 63;
    const int es = lane >> 4;
    const int f  = lane & 15;
    const float* Hk = Hc + (size_t)chunk * (size_t)N * strideA;
    // stride 16: pad slots are zeroed, all lanes real. stride 12: lanes f>=12
    // read neighbor data (slack-guarded) and are masked out of the sum.
    const float msk = (strideA == 16 || f < CW) ? 1.f : 0.f;

    int s0 = row_ptr[node], s1 = row_ptr[node + 1];
    float acc0 = 0.f, acc1 = 0.f;
    int i = s0;
    for (; i + 8 <= s1; i += 8) {
        int sA = __builtin_nontemporal_load(csr_src + i + es);
        int sB = __builtin_nontemporal_load(csr_src + i + 4 + es);
        float vA = Hk[(size_t)sA * strideA + f];
        float vB = Hk[(size_t)sB * strideA + f];
        acc0 = fmaf(vA, msk, acc0);
        acc1 = fmaf(vB, msk, acc1);
    }
    if (i + 4 <= s1) {
        int sA = __builtin_nontemporal_load(csr_src + i + es);
        acc0 = fmaf(Hk[(size_t)sA * strideA + f], msk, acc0);
        i += 4;
    }
    if (i + es < s1) {
        int sA = __builtin_nontemporal_load(csr_src + i + es);
        acc1 = fmaf(Hk[(size_t)sA * strideA + f], msk, acc1);
    }
    float acc = acc0 + acc1;
    acc += __shfl_xor(acc, 16);
    acc += __shfl_xor(acc, 32);

    float di = dinv[node];
    float self = Hk[(size_t)node * strideA + f] * msk;
    float r = fmaf(acc + self, di, bias[chunk * CW + (f < CW ? f : 0)]);

    if (es == 0 && f < CW) {
        if (OUT_ROW)
            __builtin_nontemporal_store(r, O + (size_t)node * F + chunk * CW + f);
        else
            __builtin_nontemporal_store(r, O + (size_t)chunk * (size_t)N * CW + (size_t)node * CW + f);
    }
}

// ================= fallback (atomic-scatter path, row-major) =================

__global__ void k_init_deg(float* __restrict__ deg, int N) {
    int i = blockIdx.x * blockDim.x + threadIdx.x;
    if (i < N) deg[i] = 1.0f;
}
__global__ void k_count(const int* __restrict__ dst, float* __restrict__ deg, int E) {
    int e = blockIdx.x * blockDim.x + threadIdx.x;
    if (e < E) atomicAdd(&deg[dst[e]], 1.0f);
}
__global__ void k_rsqrt(float* __restrict__ deg, int N) {
    int i = blockIdx.x * blockDim.x + threadIdx.x;
    if (i < N) deg[i] = rsqrtf(deg[i]);
}
__global__ void k_init_out(const float* __restrict__ H, const float* __restrict__ dinv,
                           const float* __restrict__ b, float* __restrict__ O, int N) {
    int idx = blockIdx.x * blockDim.x + threadIdx.x;
    if (idx >= N * F) return;
    int i = idx / F, f = idx % F;
    float di = dinv[i];
    O[idx] = fmaf(H[idx], di * di, b[f]);
}
__global__ __launch_bounds__(256) void k_scatter(const float* __restrict__ H,
                                                 const int* __restrict__ src,
                                                 const int* __restrict__ dst,
                                                 const float* __restrict__ dinv,
                                                 float* __restrict__ O, int E) {
    int t = blockIdx.x * 256 + threadIdx.x;
    int e = t >> 5;
    if (e >= E) return;
    int lf = t & 31;
    int s = src[e], d = dst[e];
    float nrm = dinv[s] * dinv[d];
    const float* hs = H + (size_t)s * F;
    float* od = O + (size_t)d * F;
#pragma unroll
    for (int j = 0; j < 3; ++j) atomicAdd(&od[lf + 32 * j], hs[lf + 32 * j] * nrm);
}

// ================= launch =================

static inline size_t align64f(size_t x) { return (x + 63) & ~(size_t)63; }

extern "C" void kernel_launch(void* const* d_in, const int* in_sizes, int n_in,
                              void* d_out, int out_size, void* d_ws, size_t ws_size,
                              hipStream_t stream) {
    const float* x  = (const float*)d_in[0];
    const float* W1 = (const float*)d_in[1];
    const float* b1 = (const float*)d_in[2];
    const float* W2 = (const float*)d_in[3];
    const float* b2 = (const float*)d_in[4];
    const float* W3 = (const float*)d_in[5];
    const float* b3 = (const float*)d_in[6];
    const int*   ei = (const int*)d_in[7];

    const int N = in_sizes[0] / F;
    const int E = in_sizes[7] / 2;
    const int* src = ei;
    const int* dst = ei + E;
    const size_t NF = (size_t)N * F;

    const int thr = 256;
    dim3 blk(thr);
    int gN  = (N + thr - 1) / thr;
    int gE  = (E + thr - 1) / thr;
    int gDen = (N + 63) / 64;
    int gGat = CHUNKS * ((N + 3) / 4);
    int nScanB = (N + SCAN_B - 1) / SCAN_B;

    // ---- workspace layout (units: floats/ints), 256B-aligned regions ----
    size_t o_rp  = align64f(N);
    size_t o_csr = o_rp + align64f((size_t)N + 1);
    size_t o_A   = o_csr + align64f((size_t)E + 4);
    size_t szA16 = (size_t)CHUNKS * N * 16 + 64;
    size_t szA12 = (size_t)CHUNKS * N * CW + 64;
    size_t szB   = (size_t)CHUNKS * N * CW;
    size_t need16 = (o_A + align64f(szA16) + szB) * 4;
    size_t need12 = (o_A + align64f(szA12) + szB) * 4;

    int strideA = (ws_size >= need16) ? 16 : 12;
    size_t o_B = o_A + align64f(strideA == 16 ? szA16 : szA12);

    float* wsf     = (float*)d_ws;
    float* dinv    = wsf;
    int*   row_ptr = (int*)(wsf + o_rp);
    int*   csr_src = (int*)(wsf + o_csr);
    float* A       = wsf + o_A;
    float* B       = wsf + o_B;
    int* hist   = (int*)A;      // temps (dead before A/B use)
    int* incl   = hist + N;
    int* cursor = (int*)B;
    int* bsum   = cursor + N;

    float* out = (float*)d_out;

    if (ws_size >= need12 && nScanB <= SCAN_B) {
        // ---- CSR build (once; reused by all 3 layers) ----
        k_zero_i<<<gN, blk, 0, stream>>>(hist, N);
        k_hist<<<gE, blk, 0, stream>>>(dst, hist, E);
        k_scan1<<<nScanB, dim3(SCAN_B), 0, stream>>>(hist, incl, bsum, N);
        k_scan2<<<1, dim3(SCAN_B), 0, stream>>>(bsum, nScanB);
        k_scan3<<<gN, blk, 0, stream>>>(incl, hist, bsum, row_ptr, cursor, N, E);
        k_dinv<<<gN, blk, 0, stream>>>(hist, dinv, N);   // before A is overwritten
        k_place<<<gE, blk, 0, stream>>>(src, dst, cursor, csr_src, E);

        // ---- layer 1 ----
        k_dense<false, false, true><<<gDen, blk, 0, stream>>>(x, W1, A, dinv, N, strideA);
        k_gather<false><<<gGat, blk, 0, stream>>>(A, csr_src, row_ptr, dinv, b1, B, N, strideA);
        // ---- layer 2 ----
        k_dense<true, true, true><<<gDen, blk, 0, stream>>>(B, W2, A, dinv, N, strideA);
        k_gather<false><<<gGat, blk, 0, stream>>>(A, csr_src, row_ptr, dinv, b2, B, N, strideA);
        // ---- layer 3 ----
        k_dense<true, true, true><<<gDen, blk, 0, stream>>>(B, W3, A, dinv, N, strideA);
        k_gather<true><<<gGat, blk, 0, stream>>>(A, csr_src, row_ptr, dinv, b3, out, N, strideA);
    } else {
        // ---- fallback: atomic-scatter path ----
        float* fdinv = (float*)d_ws;
        float* fA = fdinv + N;
        float* fB = fA + NF;
        int gNF = (int)((NF + thr - 1) / thr);
        int gSc = (int)(((size_t)E * 32 + thr - 1) / thr);
        k_init_deg<<<gN, blk, 0, stream>>>(fdinv, N);
        k_count<<<gE, blk, 0, stream>>>(dst, fdinv, E);
        k_rsqrt<<<gN, blk, 0, stream>>>(fdinv, N);
        k_dense<false, false, false><<<gDen, blk, 0, stream>>>(x, W1, fA, fdinv, N, 16);
        k_init_out<<<gNF, blk, 0, stream>>>(fA, fdinv, b1, fB, N);
        k_scatter<<<gSc, blk, 0, stream>>>(fA, src, dst, fdinv, fB, E);
        k_dense<true, false, false><<<gDen, blk, 0, stream>>>(fB, W2, fA, fdinv, N, 16);
        k_init_out<<<gNF, blk, 0, stream>>>(fA, fdinv, b2, out, N);
        k_scatter<<<gSc, blk, 0, stream>>>(fA, src, dst, fdinv, out, E);
        k_dense<true, false, false><<<gDen, blk, 0, stream>>>(out, W3, fA, fdinv, N, 16);
        k_init_out<<<gNF, blk, 0, stream>>>(fA, fdinv, b3, fB, N);
        k_scatter<<<gSc, blk, 0, stream>>>(fA, src, dst, fdinv, fB, E);
        hipMemcpyAsync(out, fB, NF * sizeof(float), hipMemcpyDeviceToDevice, stream);
    }
}

// Round 7
// 444.888 us; speedup vs baseline: 1.5446x; 1.5446x over previous
//
#include <hip/hip_runtime.h>

#define F 96
#define SCAN_B 1024
#define CHUNKS 8
#define CW 12        // logical chunk width (F / CHUNKS)
#define EWIN 2048    // LDS edge window per gather block

// Wt[c][k] stored XOR-swizzled so column-of-W float4 reads spread across banks.
#define WT_IDX(c, k) ((c) * 96 + (((k) ^ (((c) & 7) << 2))))

// ================= CSR build =================

__global__ void k_zero_i(int* __restrict__ p, int n) {
    int i = blockIdx.x * blockDim.x + threadIdx.x;
    if (i < n) p[i] = 0;
}

__global__ void k_hist(const int* __restrict__ dst, int* __restrict__ hist, int E) {
    int e = blockIdx.x * blockDim.x + threadIdx.x;
    if (e < E) atomicAdd(&hist[dst[e]], 1);
}

__global__ void k_dinv(const int* __restrict__ hist, float* __restrict__ dinv, int N) {
    int i = blockIdx.x * blockDim.x + threadIdx.x;
    if (i < N) dinv[i] = rsqrtf((float)hist[i] + 1.0f);  // +1 self-loop
}

__global__ __launch_bounds__(SCAN_B) void k_scan1(const int* __restrict__ hist,
                                                  int* __restrict__ incl,
                                                  int* __restrict__ bsum, int N) {
    __shared__ int s[SCAN_B];
    int i = blockIdx.x * SCAN_B + threadIdx.x;
    int v = (i < N) ? hist[i] : 0;
    s[threadIdx.x] = v;
    __syncthreads();
    for (int off = 1; off < SCAN_B; off <<= 1) {
        int add = (threadIdx.x >= off) ? s[threadIdx.x - off] : 0;
        __syncthreads();
        s[threadIdx.x] += add;
        __syncthreads();
    }
    if (i < N) incl[i] = s[threadIdx.x];
    if (threadIdx.x == SCAN_B - 1) bsum[blockIdx.x] = s[SCAN_B - 1];
}

__global__ __launch_bounds__(SCAN_B) void k_scan2(int* __restrict__ bsum, int nb) {
    __shared__ int s[SCAN_B];
    int v = (threadIdx.x < nb) ? bsum[threadIdx.x] : 0;
    s[threadIdx.x] = v;
    __syncthreads();
    for (int off = 1; off < SCAN_B; off <<= 1) {
        int add = (threadIdx.x >= off) ? s[threadIdx.x - off] : 0;
        __syncthreads();
        s[threadIdx.x] += add;
        __syncthreads();
    }
    if (threadIdx.x < nb) bsum[threadIdx.x] = s[threadIdx.x] - v;  // exclusive
}

__global__ void k_scan3(const int* __restrict__ incl, const int* __restrict__ hist,
                        const int* __restrict__ bsum, int* __restrict__ row_ptr,
                        int* __restrict__ cursor, int N, int E) {
    int i = blockIdx.x * blockDim.x + threadIdx.x;
    if (i < N) {
        int start = incl[i] - hist[i] + bsum[i / SCAN_B];
        row_ptr[i] = start;
        cursor[i] = start;
    }
    if (i == 0) row_ptr[N] = E;
}

__global__ void k_place(const int* __restrict__ src, const int* __restrict__ dst,
                        int* __restrict__ cursor, int* __restrict__ csr_src, int E) {
    int e = blockIdx.x * blockDim.x + threadIdx.x;
    if (e >= E) return;
    int pos = atomicAdd(&cursor[dst[e]], 1);
    csr_src[pos] = src[e];
}

// ================= dense =================
// COUT_SCALED=true: H' = dinv[row] * ((relu?)(X) @ W), written chunk-major
// [8][N][sOut] with pad slots (>=CW) zeroed. CHIN_CHUNK: input chunk-major
// [8][N][sIn] (only first CW slots read). Otherwise row-major [N][96].

template <bool RELU_IN, bool CHIN_CHUNK, bool COUT_SCALED>
__global__ __launch_bounds__(256) void k_dense(const float* __restrict__ X,
                                               const float* __restrict__ W,
                                               float* __restrict__ H,
                                               const float* __restrict__ dinv,
                                               int N, int sIn, int sOut) {
    __shared__ float Wt[96 * 96];
    __shared__ float XsOs[64][100];
    int t = threadIdx.x;
    const size_t NCin = (size_t)N * sIn;
    const size_t NCout = (size_t)N * sOut;

    for (int i = t; i < F * F; i += 256) {
        int k = i / F, c = i % F;
        Wt[WT_IDX(c, k)] = W[i];
    }
    int row0 = blockIdx.x * 64;

    // ---- stage input tile ----
    if (CHIN_CHUNK) {
        for (int q = t; q < 1536; q += 256) {
            int f = q / 192, rem = q % 192;
            int node = rem / 3, o = (rem % 3) * 4;
            int gr = row0 + node;
            float4 v = make_float4(0.f, 0.f, 0.f, 0.f);
            if (gr < N) {
                v = *reinterpret_cast<const float4*>(X + (size_t)f * NCin + (size_t)gr * sIn + o);
                if (RELU_IN) {
                    v.x = fmaxf(v.x, 0.f); v.y = fmaxf(v.y, 0.f);
                    v.z = fmaxf(v.z, 0.f); v.w = fmaxf(v.w, 0.f);
                }
            }
            *reinterpret_cast<float4*>(&XsOs[node][f * CW + o]) = v;
        }
    } else {
        for (int q = t; q < 1536; q += 256) {
            int node = q / 24, o = (q % 24) * 4;
            int gr = row0 + node;
            float4 v = make_float4(0.f, 0.f, 0.f, 0.f);
            if (gr < N) {
                v = *reinterpret_cast<const float4*>(X + (size_t)gr * F + o);
                if (RELU_IN) {
                    v.x = fmaxf(v.x, 0.f); v.y = fmaxf(v.y, 0.f);
                    v.z = fmaxf(v.z, 0.f); v.w = fmaxf(v.w, 0.f);
                }
            }
            *reinterpret_cast<float4*>(&XsOs[node][o]) = v;
        }
    }
    __syncthreads();

    // ---- compute ----
    int c2 = t & 31;
    int rg = t >> 5;
    float acc[8][3];
#pragma unroll
    for (int j = 0; j < 8; ++j) { acc[j][0] = 0.f; acc[j][1] = 0.f; acc[j][2] = 0.f; }

    for (int k4 = 0; k4 < F; k4 += 4) {
        float4 w0 = *reinterpret_cast<const float4*>(&Wt[WT_IDX(c2, k4)]);
        float4 w1 = *reinterpret_cast<const float4*>(&Wt[WT_IDX(c2 + 32, k4)]);
        float4 w2 = *reinterpret_cast<const float4*>(&Wt[WT_IDX(c2 + 64, k4)]);
#pragma unroll
        for (int j = 0; j < 8; ++j) {
            float4 xv = *reinterpret_cast<const float4*>(&XsOs[rg + 8 * j][k4]);
            acc[j][0] = fmaf(xv.x, w0.x, acc[j][0]);
            acc[j][1] = fmaf(xv.x, w1.x, acc[j][1]);
            acc[j][2] = fmaf(xv.x, w2.x, acc[j][2]);
            acc[j][0] = fmaf(xv.y, w0.y, acc[j][0]);
            acc[j][1] = fmaf(xv.y, w1.y, acc[j][1]);
            acc[j][2] = fmaf(xv.y, w2.y, acc[j][2]);
            acc[j][0] = fmaf(xv.z, w0.z, acc[j][0]);
            acc[j][1] = fmaf(xv.z, w1.z, acc[j][1]);
            acc[j][2] = fmaf(xv.z, w2.z, acc[j][2]);
            acc[j][0] = fmaf(xv.w, w0.w, acc[j][0]);
            acc[j][1] = fmaf(xv.w, w1.w, acc[j][1]);
            acc[j][2] = fmaf(xv.w, w2.w, acc[j][2]);
        }
    }
    __syncthreads();  // all k-loop reads done before overwriting XsOs

    // ---- stage output tile to LDS (scaled by dinv if COUT_SCALED) ----
#pragma unroll
    for (int j = 0; j < 8; ++j) {
        float dd = 1.f;
        if (COUT_SCALED) {
            int gr = row0 + rg + 8 * j;
            dd = (gr < N) ? dinv[gr] : 0.f;
        }
        XsOs[rg + 8 * j][c2]      = acc[j][0] * dd;
        XsOs[rg + 8 * j][c2 + 32] = acc[j][1] * dd;
        XsOs[rg + 8 * j][c2 + 64] = acc[j][2] * dd;
    }
    __syncthreads();

    // ---- coalesced store ----
    if (COUT_SCALED) {
        int nfq = sOut >> 2;  // 3 or 4 float4 per (chunk,node)
        for (int q = t; q < 512 * nfq; q += 256) {
            int ch = q / (64 * nfq);
            int rem = q % (64 * nfq);
            int node = rem / nfq;
            int o4 = (rem % nfq) * 4;
            int gr = row0 + node;
            if (gr < N) {
                float4 v = make_float4(0.f, 0.f, 0.f, 0.f);
                if (o4 < CW) v = *reinterpret_cast<const float4*>(&XsOs[node][ch * CW + o4]);
                *reinterpret_cast<float4*>(H + (size_t)ch * NCout + (size_t)gr * sOut + o4) = v;
            }
        }
    } else {
        for (int q = t; q < 1536; q += 256) {
            int node = q / 24, o = (q % 24) * 4;
            int gr = row0 + node;
            if (gr < N) {
                *reinterpret_cast<float4*>(H + (size_t)gr * F + o) =
                    *reinterpret_cast<const float4*>(&XsOs[node][o]);
            }
        }
    }
}

// ================= gather (chunk x XCD, slot-per-node, LDS-staged CSR) ======
// chunk = blockIdx&7 (XCD pin). Block = 16 slots x 16 lanes; slot owns one
// node, lane = feature. Block's contiguous CSR range staged into LDS in
// EWIN windows with coalesced loads; inner loop: ds_read(broadcast) -> L2
// H' load -> add (two independent chains). Epilogue: no reduction needed.
// O[d] = dinv[d] * (sum_e H'[src_e] + H'[d]) + b   (H' prescaled by dinv)

template <bool OUT_ROW>
__global__ __launch_bounds__(256) void k_gather(const float* __restrict__ Hc,
                                                const int* __restrict__ csr_src,
                                                const int* __restrict__ row_ptr,
                                                const float* __restrict__ dinv,
                                                const float* __restrict__ bias,
                                                float* __restrict__ O,
                                                int N, int sA, int sB) {
    __shared__ int eidx[EWIN];
    const int tid = threadIdx.x;
    const int chunk = blockIdx.x & (CHUNKS - 1);
    const int nb0 = (blockIdx.x >> 3) * 16;
    const int slot = tid >> 4;
    const int f = tid & 15;
    const int node = nb0 + slot;
    const float* Hk = Hc + (size_t)chunk * (size_t)N * sA;

    float bf = (f < CW) ? bias[chunk * CW + f] : 0.f;
    const int nEnd = min(nb0 + 16, N);
    const int B0 = row_ptr[nb0];
    const int B1 = row_ptr[nEnd];
    int s0 = 0, s1 = 0;
    if (node < N) { s0 = row_ptr[node]; s1 = row_ptr[node + 1]; }

    float acc0 = 0.f, acc1 = 0.f;
    for (int wb = B0; wb < B1; wb += EWIN) {
        int wcnt = min(EWIN, B1 - wb);
        __syncthreads();  // previous window fully consumed
        for (int q = tid; q < wcnt; q += 256)
            eidx[q] = __builtin_nontemporal_load(csr_src + wb + q);
        __syncthreads();
        int e  = max(s0, wb);
        int e1 = min(s1, wb + wcnt);
        for (; e + 1 < e1; e += 2) {
            int i0 = eidx[e - wb];
            int i1 = eidx[e - wb + 1];
            acc0 += Hk[(size_t)i0 * sA + f];
            acc1 += Hk[(size_t)i1 * sA + f];
        }
        if (e < e1) acc0 += Hk[(size_t)eidx[e - wb] * sA + f];
    }
    if (node >= N) return;

    float di = dinv[node];
    float self = Hk[(size_t)node * sA + f];
    float r = fmaf(acc0 + acc1 + self, di, bf);

    if (OUT_ROW) {
        if (f < CW) O[(size_t)node * F + chunk * CW + f] = r;
    } else if (sB == 16) {
        O[(size_t)chunk * (size_t)N * 16 + (size_t)node * 16 + f] = r;
    } else {
        if (f < CW) O[(size_t)chunk * (size_t)N * CW + (size_t)node * CW + f] = r;
    }
}

// ================= fallback (atomic-scatter path, row-major) =================

__global__ void k_init_deg(float* __restrict__ deg, int N) {
    int i = blockIdx.x * blockDim.x + threadIdx.x;
    if (i < N) deg[i] = 1.0f;
}
__global__ void k_count(const int* __restrict__ dst, float* __restrict__ deg, int E) {
    int e = blockIdx.x * blockDim.x + threadIdx.x;
    if (e < E) atomicAdd(&deg[dst[e]], 1.0f);
}
__global__ void k_rsqrt(float* __restrict__ deg, int N) {
    int i = blockIdx.x * blockDim.x + threadIdx.x;
    if (i < N) deg[i] = rsqrtf(deg[i]);
}
__global__ void k_init_out(const float* __restrict__ H, const float* __restrict__ dinv,
                           const float* __restrict__ b, float* __restrict__ O, int N) {
    int idx = blockIdx.x * blockDim.x + threadIdx.x;
    if (idx >= N * F) return;
    int i = idx / F, f = idx % F;
    float di = dinv[i];
    O[idx] = fmaf(H[idx], di * di, b[f]);
}
__global__ __launch_bounds__(256) void k_scatter(const float* __restrict__ H,
                                                 const int* __restrict__ src,
                                                 const int* __restrict__ dst,
                                                 const float* __restrict__ dinv,
                                                 float* __restrict__ O, int E) {
    int t = blockIdx.x * 256 + threadIdx.x;
    int e = t >> 5;
    if (e >= E) return;
    int lf = t & 31;
    int s = src[e], d = dst[e];
    float nrm = dinv[s] * dinv[d];
    const float* hs = H + (size_t)s * F;
    float* od = O + (size_t)d * F;
#pragma unroll
    for (int j = 0; j < 3; ++j) atomicAdd(&od[lf + 32 * j], hs[lf + 32 * j] * nrm);
}

// ================= launch =================

static inline size_t align64f(size_t x) { return (x + 63) & ~(size_t)63; }

extern "C" void kernel_launch(void* const* d_in, const int* in_sizes, int n_in,
                              void* d_out, int out_size, void* d_ws, size_t ws_size,
                              hipStream_t stream) {
    const float* x  = (const float*)d_in[0];
    const float* W1 = (const float*)d_in[1];
    const float* b1 = (const float*)d_in[2];
    const float* W2 = (const float*)d_in[3];
    const float* b2 = (const float*)d_in[4];
    const float* W3 = (const float*)d_in[5];
    const float* b3 = (const float*)d_in[6];
    const int*   ei = (const int*)d_in[7];

    const int N = in_sizes[0] / F;
    const int E = in_sizes[7] / 2;
    const int* src = ei;
    const int* dst = ei + E;
    const size_t NF = (size_t)N * F;

    const int thr = 256;
    dim3 blk(thr);
    int gN  = (N + thr - 1) / thr;
    int gE  = (E + thr - 1) / thr;
    int gDen = (N + 63) / 64;
    int gGat = CHUNKS * ((N + 15) / 16);
    int nScanB = (N + SCAN_B - 1) / SCAN_B;

    // ---- workspace layout (units: floats/ints) ----
    size_t o_rp  = align64f(N);                     // dinv in [0,N)
    size_t o_csr = o_rp + align64f((size_t)N + 1);
    size_t o_A   = o_csr + align64f((size_t)E + 4);
    size_t szA16 = (size_t)CHUNKS * N * 16 + 64;
    size_t szA12 = (size_t)CHUNKS * N * 12 + 64;
    size_t t1616 = (o_A + align64f(szA16) + szA16) * 4;
    size_t t1612 = (o_A + align64f(szA16) + szA12) * 4;
    size_t t1212 = (o_A + align64f(szA12) + szA12) * 4;

    int sA = 16, sB = 16;
    size_t o_B;
    bool csr_ok = (nScanB <= SCAN_B);
    if (ws_size >= t1616)      { sA = 16; sB = 16; o_B = o_A + align64f(szA16); }
    else if (ws_size >= t1612) { sA = 16; sB = 12; o_B = o_A + align64f(szA16); }
    else if (ws_size >= t1212) { sA = 12; sB = 12; o_B = o_A + align64f(szA12); }
    else csr_ok = false;

    float* wsf     = (float*)d_ws;
    float* dinv    = wsf;
    int*   row_ptr = (int*)(wsf + o_rp);
    int*   csr_src = (int*)(wsf + o_csr);
    float* A       = wsf + (csr_ok ? o_A : 0);
    float* B       = wsf + (csr_ok ? o_B : 0);
    int* hist   = (int*)A;      // temps (dead before A/B use)
    int* incl   = hist + N;
    int* cursor = (int*)B;
    int* bsum   = cursor + N;

    float* out = (float*)d_out;

    if (csr_ok) {
        // ---- CSR build (once; reused by all 3 layers) ----
        k_zero_i<<<gN, blk, 0, stream>>>(hist, N);
        k_hist<<<gE, blk, 0, stream>>>(dst, hist, E);
        k_scan1<<<nScanB, dim3(SCAN_B), 0, stream>>>(hist, incl, bsum, N);
        k_scan2<<<1, dim3(SCAN_B), 0, stream>>>(bsum, nScanB);
        k_scan3<<<gN, blk, 0, stream>>>(incl, hist, bsum, row_ptr, cursor, N, E);
        k_dinv<<<gN, blk, 0, stream>>>(hist, dinv, N);   // before A is overwritten
        k_place<<<gE, blk, 0, stream>>>(src, dst, cursor, csr_src, E);

        // ---- layer 1 ----
        k_dense<false, false, true><<<gDen, blk, 0, stream>>>(x, W1, A, dinv, N, F, sA);
        k_gather<false><<<gGat, blk, 0, stream>>>(A, csr_src, row_ptr, dinv, b1, B, N, sA, sB);
        // ---- layer 2 ----
        k_dense<true, true, true><<<gDen, blk, 0, stream>>>(B, W2, A, dinv, N, sB, sA);
        k_gather<false><<<gGat, blk, 0, stream>>>(A, csr_src, row_ptr, dinv, b2, B, N, sA, sB);
        // ---- layer 3 ----
        k_dense<true, true, true><<<gDen, blk, 0, stream>>>(B, W3, A, dinv, N, sB, sA);
        k_gather<true><<<gGat, blk, 0, stream>>>(A, csr_src, row_ptr, dinv, b3, out, N, sA, 0);
    } else {
        // ---- fallback: atomic-scatter path ----
        float* fdinv = (float*)d_ws;
        float* fA = fdinv + N;
        float* fB = fA + NF;
        int gNF = (int)((NF + thr - 1) / thr);
        int gSc = (int)(((size_t)E * 32 + thr - 1) / thr);
        k_init_deg<<<gN, blk, 0, stream>>>(fdinv, N);
        k_count<<<gE, blk, 0, stream>>>(dst, fdinv, E);
        k_rsqrt<<<gN, blk, 0, stream>>>(fdinv, N);
        k_dense<false, false, false><<<gDen, blk, 0, stream>>>(x, W1, fA, fdinv, N, F, F);
        k_init_out<<<gNF, blk, 0, stream>>>(fA, fdinv, b1, fB, N);
        k_scatter<<<gSc, blk, 0, stream>>>(fA, src, dst, fdinv, fB, E);
        k_dense<true, false, false><<<gDen, blk, 0, stream>>>(fB, W2, fA, fdinv, N, F, F);
        k_init_out<<<gNF, blk, 0, stream>>>(fA, fdinv, b2, out, N);
        k_scatter<<<gSc, blk, 0, stream>>>(fA, src, dst, fdinv, out, E);
        k_dense<true, false, false><<<gDen, blk, 0, stream>>>(out, W3, fA, fdinv, N, F, F);
        k_init_out<<<gNF, blk, 0, stream>>>(fA, fdinv, b3, fB, N);
        k_scatter<<<gSc, blk, 0, stream>>>(fA, src, dst, fdinv, fB, E);
        hipMemcpyAsync(out, fB, NF * sizeof(float), hipMemcpyDeviceToDevice, stream);
    }
}

// Round 8
// 404.671 us; speedup vs baseline: 1.6981x; 1.0994x over previous
//
#include <hip/hip_runtime.h>

#define F 96
#define SCAN_B 1024
#define CHUNKS 8
#define CW 12        // logical chunk width (F / CHUNKS)
#define EWIN 2048    // LDS edge window per gather block

// Wt[c][k] stored XOR-swizzled so column-of-W float4 reads spread across banks.
#define WT_IDX(c, k) ((c) * 96 + (((k) ^ (((c) & 7) << 2))))

// ================= CSR build =================

__global__ void k_zero_i(int* __restrict__ p, int n) {
    int i = blockIdx.x * blockDim.x + threadIdx.x;
    if (i < n) p[i] = 0;
}

__global__ void k_hist(const int* __restrict__ dst, int* __restrict__ hist, int E) {
    int e = blockIdx.x * blockDim.x + threadIdx.x;
    if (e < E) atomicAdd(&hist[dst[e]], 1);
}

__global__ void k_dinv(const int* __restrict__ hist, float* __restrict__ dinv, int N) {
    int i = blockIdx.x * blockDim.x + threadIdx.x;
    if (i < N) dinv[i] = rsqrtf((float)hist[i] + 1.0f);  // +1 self-loop
}

__global__ __launch_bounds__(SCAN_B) void k_scan1(const int* __restrict__ hist,
                                                  int* __restrict__ incl,
                                                  int* __restrict__ bsum, int N) {
    __shared__ int s[SCAN_B];
    int i = blockIdx.x * SCAN_B + threadIdx.x;
    int v = (i < N) ? hist[i] : 0;
    s[threadIdx.x] = v;
    __syncthreads();
    for (int off = 1; off < SCAN_B; off <<= 1) {
        int add = (threadIdx.x >= off) ? s[threadIdx.x - off] : 0;
        __syncthreads();
        s[threadIdx.x] += add;
        __syncthreads();
    }
    if (i < N) incl[i] = s[threadIdx.x];
    if (threadIdx.x == SCAN_B - 1) bsum[blockIdx.x] = s[SCAN_B - 1];
}

__global__ __launch_bounds__(SCAN_B) void k_scan2(int* __restrict__ bsum, int nb) {
    __shared__ int s[SCAN_B];
    int v = (threadIdx.x < nb) ? bsum[threadIdx.x] : 0;
    s[threadIdx.x] = v;
    __syncthreads();
    for (int off = 1; off < SCAN_B; off <<= 1) {
        int add = (threadIdx.x >= off) ? s[threadIdx.x - off] : 0;
        __syncthreads();
        s[threadIdx.x] += add;
        __syncthreads();
    }
    if (threadIdx.x < nb) bsum[threadIdx.x] = s[threadIdx.x] - v;  // exclusive
}

__global__ void k_scan3(const int* __restrict__ incl, const int* __restrict__ hist,
                        const int* __restrict__ bsum, int* __restrict__ row_ptr,
                        int* __restrict__ cursor, int N, int E) {
    int i = blockIdx.x * blockDim.x + threadIdx.x;
    if (i < N) {
        int start = incl[i] - hist[i] + bsum[i / SCAN_B];
        row_ptr[i] = start;
        cursor[i] = start;
    }
    if (i == 0) row_ptr[N] = E;
}

__global__ void k_place(const int* __restrict__ src, const int* __restrict__ dst,
                        int* __restrict__ cursor, int* __restrict__ csr_src, int E) {
    int e = blockIdx.x * blockDim.x + threadIdx.x;
    if (e >= E) return;
    int pos = atomicAdd(&cursor[dst[e]], 1);
    csr_src[pos] = src[e];
}

// ================= dense =================
// COUT_SCALED=true: H' = dinv[row] * ((relu?)(X) @ W), written chunk-major
// [8][N][sOut] with pad slots (>=CW) zeroed. CHIN_CHUNK: input chunk-major
// [8][N][sIn] (only first CW slots read). Otherwise row-major [N][96].

template <bool RELU_IN, bool CHIN_CHUNK, bool COUT_SCALED>
__global__ __launch_bounds__(256) void k_dense(const float* __restrict__ X,
                                               const float* __restrict__ W,
                                               float* __restrict__ H,
                                               const float* __restrict__ dinv,
                                               int N, int sIn, int sOut) {
    __shared__ float Wt[96 * 96];
    __shared__ float XsOs[64][100];
    int t = threadIdx.x;
    const size_t NCin = (size_t)N * sIn;
    const size_t NCout = (size_t)N * sOut;

    for (int i = t; i < F * F; i += 256) {
        int k = i / F, c = i % F;
        Wt[WT_IDX(c, k)] = W[i];
    }
    int row0 = blockIdx.x * 64;

    // ---- stage input tile ----
    if (CHIN_CHUNK) {
        for (int q = t; q < 1536; q += 256) {
            int f = q / 192, rem = q % 192;
            int node = rem / 3, o = (rem % 3) * 4;
            int gr = row0 + node;
            float4 v = make_float4(0.f, 0.f, 0.f, 0.f);
            if (gr < N) {
                v = *reinterpret_cast<const float4*>(X + (size_t)f * NCin + (size_t)gr * sIn + o);
                if (RELU_IN) {
                    v.x = fmaxf(v.x, 0.f); v.y = fmaxf(v.y, 0.f);
                    v.z = fmaxf(v.z, 0.f); v.w = fmaxf(v.w, 0.f);
                }
            }
            *reinterpret_cast<float4*>(&XsOs[node][f * CW + o]) = v;
        }
    } else {
        for (int q = t; q < 1536; q += 256) {
            int node = q / 24, o = (q % 24) * 4;
            int gr = row0 + node;
            float4 v = make_float4(0.f, 0.f, 0.f, 0.f);
            if (gr < N) {
                v = *reinterpret_cast<const float4*>(X + (size_t)gr * F + o);
                if (RELU_IN) {
                    v.x = fmaxf(v.x, 0.f); v.y = fmaxf(v.y, 0.f);
                    v.z = fmaxf(v.z, 0.f); v.w = fmaxf(v.w, 0.f);
                }
            }
            *reinterpret_cast<float4*>(&XsOs[node][o]) = v;
        }
    }
    __syncthreads();

    // ---- compute ----
    int c2 = t & 31;
    int rg = t >> 5;
    float acc[8][3];
#pragma unroll
    for (int j = 0; j < 8; ++j) { acc[j][0] = 0.f; acc[j][1] = 0.f; acc[j][2] = 0.f; }

    for (int k4 = 0; k4 < F; k4 += 4) {
        float4 w0 = *reinterpret_cast<const float4*>(&Wt[WT_IDX(c2, k4)]);
        float4 w1 = *reinterpret_cast<const float4*>(&Wt[WT_IDX(c2 + 32, k4)]);
        float4 w2 = *reinterpret_cast<const float4*>(&Wt[WT_IDX(c2 + 64, k4)]);
#pragma unroll
        for (int j = 0; j < 8; ++j) {
            float4 xv = *reinterpret_cast<const float4*>(&XsOs[rg + 8 * j][k4]);
            acc[j][0] = fmaf(xv.x, w0.x, acc[j][0]);
            acc[j][1] = fmaf(xv.x, w1.x, acc[j][1]);
            acc[j][2] = fmaf(xv.x, w2.x, acc[j][2]);
            acc[j][0] = fmaf(xv.y, w0.y, acc[j][0]);
            acc[j][1] = fmaf(xv.y, w1.y, acc[j][1]);
            acc[j][2] = fmaf(xv.y, w2.y, acc[j][2]);
            acc[j][0] = fmaf(xv.z, w0.z, acc[j][0]);
            acc[j][1] = fmaf(xv.z, w1.z, acc[j][1]);
            acc[j][2] = fmaf(xv.z, w2.z, acc[j][2]);
            acc[j][0] = fmaf(xv.w, w0.w, acc[j][0]);
            acc[j][1] = fmaf(xv.w, w1.w, acc[j][1]);
            acc[j][2] = fmaf(xv.w, w2.w, acc[j][2]);
        }
    }
    __syncthreads();  // all k-loop reads done before overwriting XsOs

    // ---- stage output tile to LDS (scaled by dinv if COUT_SCALED) ----
#pragma unroll
    for (int j = 0; j < 8; ++j) {
        float dd = 1.f;
        if (COUT_SCALED) {
            int gr = row0 + rg + 8 * j;
            dd = (gr < N) ? dinv[gr] : 0.f;
        }
        XsOs[rg + 8 * j][c2]      = acc[j][0] * dd;
        XsOs[rg + 8 * j][c2 + 32] = acc[j][1] * dd;
        XsOs[rg + 8 * j][c2 + 64] = acc[j][2] * dd;
    }
    __syncthreads();

    // ---- coalesced store ----
    if (COUT_SCALED) {
        int nfq = sOut >> 2;  // 3 or 4 float4 per (chunk,node)
        for (int q = t; q < 512 * nfq; q += 256) {
            int ch = q / (64 * nfq);
            int rem = q % (64 * nfq);
            int node = rem / nfq;
            int o4 = (rem % nfq) * 4;
            int gr = row0 + node;
            if (gr < N) {
                float4 v = make_float4(0.f, 0.f, 0.f, 0.f);
                if (o4 < CW) v = *reinterpret_cast<const float4*>(&XsOs[node][ch * CW + o4]);
                *reinterpret_cast<float4*>(H + (size_t)ch * NCout + (size_t)gr * sOut + o4) = v;
            }
        }
    } else {
        for (int q = t; q < 1536; q += 256) {
            int node = q / 24, o = (q % 24) * 4;
            int gr = row0 + node;
            if (gr < N) {
                *reinterpret_cast<float4*>(H + (size_t)gr * F + o) =
                    *reinterpret_cast<const float4*>(&XsOs[node][o]);
            }
        }
    }
}

// ================= gather v2 (chunk x XCD, float4 slots, degree-sorted) =====
// Requires sA == 16 (padded chunk rows). Block = 64 nodes; slot = 4 lanes x
// float4 (covers the full 64-B chunk row -> one line per edge-visit, 16 lines
// per load instruction). Nodes rank-sorted by degree so each wave's 16 slots
// have similar degree (divergence ~mean, not max). CSR range staged in LDS.
// O[d] = dinv[d] * (sum_e H'[src_e] + H'[d]) + b   (H' prescaled by dinv)

template <bool OUT_ROW>
__global__ __launch_bounds__(256) void k_gather16(const float* __restrict__ Hc,
                                                  const int* __restrict__ csr_src,
                                                  const int* __restrict__ row_ptr,
                                                  const float* __restrict__ dinv,
                                                  const float* __restrict__ bias,
                                                  float* __restrict__ O,
                                                  int N, int sB) {
    __shared__ int eidx[EWIN];
    __shared__ int sdeg[64];
    __shared__ int ord[64];
    const int tid = threadIdx.x;
    const int chunk = blockIdx.x & (CHUNKS - 1);
    const int nb0 = (blockIdx.x >> 3) * 64;
    const float* Hk = Hc + (size_t)chunk * (size_t)N * 16;

    const int nEnd = min(nb0 + 64, N);
    const int nloc = nEnd - nb0;

    // ---- rank-sort the block's 64 nodes by degree (ascending) ----
    if (tid < 64) {
        int nd = nb0 + tid;
        sdeg[tid] = (nd < N) ? (row_ptr[nd + 1] - row_ptr[nd]) : -1;
    }
    __syncthreads();
    if (tid < 64) {
        int d = sdeg[tid];
        int r = 0;
#pragma unroll 8
        for (int j = 0; j < 64; ++j) {
            int dj = sdeg[j];
            r += (dj < d) || (dj == d && j < tid);
        }
        ord[r] = tid;
    }
    __syncthreads();

    const int slot = tid >> 2;        // 0..63 (wave = 16 consecutive ranks)
    const int fl = (tid & 3) * 4;     // feature base within padded row
    int node = -1, s0 = 0, s1 = 0;
    {
        int on = ord[slot];
        int nd = nb0 + on;
        if (on < nloc && nd < N) { node = nd; s0 = row_ptr[nd]; s1 = row_ptr[nd + 1]; }
    }

    float4 a0 = make_float4(0.f, 0.f, 0.f, 0.f);
    float4 a1 = make_float4(0.f, 0.f, 0.f, 0.f);
    const int B0 = row_ptr[nb0];
    const int B1 = row_ptr[nEnd];
    for (int wb = B0; wb < B1; wb += EWIN) {
        int wcnt = min(EWIN, B1 - wb);
        __syncthreads();  // previous window fully consumed
        for (int q = tid; q < wcnt; q += 256)
            eidx[q] = __builtin_nontemporal_load(csr_src + wb + q);
        __syncthreads();
        int e  = max(s0, wb);
        int e1 = min(s1, wb + wcnt);
        for (; e + 1 < e1; e += 2) {
            int i0 = eidx[e - wb];
            int i1 = eidx[e - wb + 1];
            float4 v0 = *reinterpret_cast<const float4*>(Hk + (size_t)i0 * 16 + fl);
            float4 v1 = *reinterpret_cast<const float4*>(Hk + (size_t)i1 * 16 + fl);
            a0.x += v0.x; a0.y += v0.y; a0.z += v0.z; a0.w += v0.w;
            a1.x += v1.x; a1.y += v1.y; a1.z += v1.z; a1.w += v1.w;
        }
        if (e < e1) {
            int i0 = eidx[e - wb];
            float4 v0 = *reinterpret_cast<const float4*>(Hk + (size_t)i0 * 16 + fl);
            a0.x += v0.x; a0.y += v0.y; a0.z += v0.z; a0.w += v0.w;
        }
    }
    if (node < 0) return;

    float di = dinv[node];
    float4 self = *reinterpret_cast<const float4*>(Hk + (size_t)node * 16 + fl);
    float4 b4 = make_float4(0.f, 0.f, 0.f, 0.f);
    if (fl < CW) b4 = *reinterpret_cast<const float4*>(bias + chunk * CW + fl);
    float4 r;
    r.x = fmaf(a0.x + a1.x + self.x, di, b4.x);
    r.y = fmaf(a0.y + a1.y + self.y, di, b4.y);
    r.z = fmaf(a0.z + a1.z + self.z, di, b4.z);
    r.w = fmaf(a0.w + a1.w + self.w, di, b4.w);

    if (OUT_ROW) {
        if (fl < CW)
            *reinterpret_cast<float4*>(O + (size_t)node * F + chunk * CW + fl) = r;
    } else {
        // sB == 16: full padded row written (pads garbage, never read)
        *reinterpret_cast<float4*>(O + (size_t)chunk * (size_t)N * 16 + (size_t)node * 16 + fl) = r;
    }
}

// ================= gather legacy (stride-12-capable, slot-per-node) =========

template <bool OUT_ROW>
__global__ __launch_bounds__(256) void k_gather(const float* __restrict__ Hc,
                                                const int* __restrict__ csr_src,
                                                const int* __restrict__ row_ptr,
                                                const float* __restrict__ dinv,
                                                const float* __restrict__ bias,
                                                float* __restrict__ O,
                                                int N, int sA, int sB) {
    __shared__ int eidx[EWIN];
    const int tid = threadIdx.x;
    const int chunk = blockIdx.x & (CHUNKS - 1);
    const int nb0 = (blockIdx.x >> 3) * 16;
    const int slot = tid >> 4;
    const int f = tid & 15;
    const int node = nb0 + slot;
    const float* Hk = Hc + (size_t)chunk * (size_t)N * sA;

    float bf = (f < CW) ? bias[chunk * CW + f] : 0.f;
    const int nEnd = min(nb0 + 16, N);
    const int B0 = row_ptr[nb0];
    const int B1 = row_ptr[nEnd];
    int s0 = 0, s1 = 0;
    if (node < N) { s0 = row_ptr[node]; s1 = row_ptr[node + 1]; }

    float acc0 = 0.f, acc1 = 0.f;
    for (int wb = B0; wb < B1; wb += EWIN) {
        int wcnt = min(EWIN, B1 - wb);
        __syncthreads();
        for (int q = tid; q < wcnt; q += 256)
            eidx[q] = __builtin_nontemporal_load(csr_src + wb + q);
        __syncthreads();
        int e  = max(s0, wb);
        int e1 = min(s1, wb + wcnt);
        for (; e + 1 < e1; e += 2) {
            int i0 = eidx[e - wb];
            int i1 = eidx[e - wb + 1];
            acc0 += Hk[(size_t)i0 * sA + f];
            acc1 += Hk[(size_t)i1 * sA + f];
        }
        if (e < e1) acc0 += Hk[(size_t)eidx[e - wb] * sA + f];
    }
    if (node >= N) return;

    float di = dinv[node];
    float self = Hk[(size_t)node * sA + f];
    float r = fmaf(acc0 + acc1 + self, di, bf);

    if (OUT_ROW) {
        if (f < CW) O[(size_t)node * F + chunk * CW + f] = r;
    } else if (sB == 16) {
        O[(size_t)chunk * (size_t)N * 16 + (size_t)node * 16 + f] = r;
    } else {
        if (f < CW) O[(size_t)chunk * (size_t)N * CW + (size_t)node * CW + f] = r;
    }
}

// ================= fallback (atomic-scatter path, row-major) =================

__global__ void k_init_deg(float* __restrict__ deg, int N) {
    int i = blockIdx.x * blockDim.x + threadIdx.x;
    if (i < N) deg[i] = 1.0f;
}
__global__ void k_count(const int* __restrict__ dst, float* __restrict__ deg, int E) {
    int e = blockIdx.x * blockDim.x + threadIdx.x;
    if (e < E) atomicAdd(&deg[dst[e]], 1.0f);
}
__global__ void k_rsqrt(float* __restrict__ deg, int N) {
    int i = blockIdx.x * blockDim.x + threadIdx.x;
    if (i < N) deg[i] = rsqrtf(deg[i]);
}
__global__ void k_init_out(const float* __restrict__ H, const float* __restrict__ dinv,
                           const float* __restrict__ b, float* __restrict__ O, int N) {
    int idx = blockIdx.x * blockDim.x + threadIdx.x;
    if (idx >= N * F) return;
    int i = idx / F, f = idx % F;
    float di = dinv[i];
    O[idx] = fmaf(H[idx], di * di, b[f]);
}
__global__ __launch_bounds__(256) void k_scatter(const float* __restrict__ H,
                                                 const int* __restrict__ src,
                                                 const int* __restrict__ dst,
                                                 const float* __restrict__ dinv,
                                                 float* __restrict__ O, int E) {
    int t = blockIdx.x * 256 + threadIdx.x;
    int e = t >> 5;
    if (e >= E) return;
    int lf = t & 31;
    int s = src[e], d = dst[e];
    float nrm = dinv[s] * dinv[d];
    const float* hs = H + (size_t)s * F;
    float* od = O + (size_t)d * F;
#pragma unroll
    for (int j = 0; j < 3; ++j) atomicAdd(&od[lf + 32 * j], hs[lf + 32 * j] * nrm);
}

// ================= launch =================

static inline size_t align64f(size_t x) { return (x + 63) & ~(size_t)63; }

extern "C" void kernel_launch(void* const* d_in, const int* in_sizes, int n_in,
                              void* d_out, int out_size, void* d_ws, size_t ws_size,
                              hipStream_t stream) {
    const float* x  = (const float*)d_in[0];
    const float* W1 = (const float*)d_in[1];
    const float* b1 = (const float*)d_in[2];
    const float* W2 = (const float*)d_in[3];
    const float* b2 = (const float*)d_in[4];
    const float* W3 = (const float*)d_in[5];
    const float* b3 = (const float*)d_in[6];
    const int*   ei = (const int*)d_in[7];

    const int N = in_sizes[0] / F;
    const int E = in_sizes[7] / 2;
    const int* src = ei;
    const int* dst = ei + E;
    const size_t NF = (size_t)N * F;

    const int thr = 256;
    dim3 blk(thr);
    int gN  = (N + thr - 1) / thr;
    int gE  = (E + thr - 1) / thr;
    int gDen = (N + 63) / 64;
    int gGat16 = CHUNKS * ((N + 63) / 64);
    int gGatLeg = CHUNKS * ((N + 15) / 16);
    int nScanB = (N + SCAN_B - 1) / SCAN_B;

    // ---- workspace layout (units: floats/ints) ----
    size_t o_rp  = align64f(N);                     // dinv in [0,N)
    size_t o_csr = o_rp + align64f((size_t)N + 1);
    size_t o_A   = o_csr + align64f((size_t)E + 4);
    size_t szA16 = (size_t)CHUNKS * N * 16 + 64;
    size_t szA12 = (size_t)CHUNKS * N * 12 + 64;
    size_t t1616 = (o_A + align64f(szA16) + szA16) * 4;
    size_t t1612 = (o_A + align64f(szA16) + szA12) * 4;
    size_t t1212 = (o_A + align64f(szA12) + szA12) * 4;

    int sA = 16, sB = 16;
    size_t o_B = 0;
    bool csr_ok = (nScanB <= SCAN_B);
    bool fast16 = false;
    if (ws_size >= t1616)      { sA = 16; sB = 16; o_B = o_A + align64f(szA16); fast16 = true; }
    else if (ws_size >= t1612) { sA = 16; sB = 12; o_B = o_A + align64f(szA16); }
    else if (ws_size >= t1212) { sA = 12; sB = 12; o_B = o_A + align64f(szA12); }
    else csr_ok = false;

    float* wsf     = (float*)d_ws;
    float* dinv    = wsf;
    int*   row_ptr = (int*)(wsf + o_rp);
    int*   csr_src = (int*)(wsf + o_csr);
    float* A       = wsf + (csr_ok ? o_A : 0);
    float* B       = wsf + (csr_ok ? o_B : 0);
    int* hist   = (int*)A;      // temps (dead before A/B use)
    int* incl   = hist + N;
    int* cursor = (int*)B;
    int* bsum   = cursor + N;

    float* out = (float*)d_out;

    if (csr_ok) {
        // ---- CSR build (once; reused by all 3 layers) ----
        k_zero_i<<<gN, blk, 0, stream>>>(hist, N);
        k_hist<<<gE, blk, 0, stream>>>(dst, hist, E);
        k_scan1<<<nScanB, dim3(SCAN_B), 0, stream>>>(hist, incl, bsum, N);
        k_scan2<<<1, dim3(SCAN_B), 0, stream>>>(bsum, nScanB);
        k_scan3<<<gN, blk, 0, stream>>>(incl, hist, bsum, row_ptr, cursor, N, E);
        k_dinv<<<gN, blk, 0, stream>>>(hist, dinv, N);   // before A is overwritten
        k_place<<<gE, blk, 0, stream>>>(src, dst, cursor, csr_src, E);

        if (fast16) {
            // ---- layer 1 ----
            k_dense<false, false, true><<<gDen, blk, 0, stream>>>(x, W1, A, dinv, N, F, 16);
            k_gather16<false><<<gGat16, blk, 0, stream>>>(A, csr_src, row_ptr, dinv, b1, B, N, 16);
            // ---- layer 2 ----
            k_dense<true, true, true><<<gDen, blk, 0, stream>>>(B, W2, A, dinv, N, 16, 16);
            k_gather16<false><<<gGat16, blk, 0, stream>>>(A, csr_src, row_ptr, dinv, b2, B, N, 16);
            // ---- layer 3 ----
            k_dense<true, true, true><<<gDen, blk, 0, stream>>>(B, W3, A, dinv, N, 16, 16);
            k_gather16<true><<<gGat16, blk, 0, stream>>>(A, csr_src, row_ptr, dinv, b3, out, N, 0);
        } else {
            // ---- layer 1 ----
            k_dense<false, false, true><<<gDen, blk, 0, stream>>>(x, W1, A, dinv, N, F, sA);
            k_gather<false><<<gGatLeg, blk, 0, stream>>>(A, csr_src, row_ptr, dinv, b1, B, N, sA, sB);
            // ---- layer 2 ----
            k_dense<true, true, true><<<gDen, blk, 0, stream>>>(B, W2, A, dinv, N, sB, sA);
            k_gather<false><<<gGatLeg, blk, 0, stream>>>(A, csr_src, row_ptr, dinv, b2, B, N, sA, sB);
            // ---- layer 3 ----
            k_dense<true, true, true><<<gDen, blk, 0, stream>>>(B, W3, A, dinv, N, sB, sA);
            k_gather<true><<<gGatLeg, blk, 0, stream>>>(A, csr_src, row_ptr, dinv, b3, out, N, sA, 0);
        }
    } else {
        // ---- fallback: atomic-scatter path ----
        float* fdinv = (float*)d_ws;
        float* fA = fdinv + N;
        float* fB = fA + NF;
        int gNF = (int)((NF + thr - 1) / thr);
        int gSc = (int)(((size_t)E * 32 + thr - 1) / thr);
        k_init_deg<<<gN, blk, 0, stream>>>(fdinv, N);
        k_count<<<gE, blk, 0, stream>>>(dst, fdinv, E);
        k_rsqrt<<<gN, blk, 0, stream>>>(fdinv, N);
        k_dense<false, false, false><<<gDen, blk, 0, stream>>>(x, W1, fA, fdinv, N, F, F);
        k_init_out<<<gNF, blk, 0, stream>>>(fA, fdinv, b1, fB, N);
        k_scatter<<<gSc, blk, 0, stream>>>(fA, src, dst, fdinv, fB, E);
        k_dense<true, false, false><<<gDen, blk, 0, stream>>>(fB, W2, fA, fdinv, N, F, F);
        k_init_out<<<gNF, blk, 0, stream>>>(fA, fdinv, b2, out, N);
        k_scatter<<<gSc, blk, 0, stream>>>(fA, src, dst, fdinv, out, E);
        k_dense<true, false, false><<<gDen, blk, 0, stream>>>(out, W3, fA, fdinv, N, F, F);
        k_init_out<<<gNF, blk, 0, stream>>>(fA, fdinv, b3, fB, N);
        k_scatter<<<gSc, blk, 0, stream>>>(fA, src, dst, fdinv, fB, E);
        hipMemcpyAsync(out, fB, NF * sizeof(float), hipMemcpyDeviceToDevice, stream);
    }
}

// Round 11
// 401.141 us; speedup vs baseline: 1.7131x; 1.0088x over previous
//
#include <hip/hip_runtime.h>

#define F 96
#define SCAN_B 1024
#define CHUNKS 8
#define CW 12        // logical chunk width (F / CHUNKS)
#define EWIN 2048    // LDS edge window per gather block

// Wt[c][k] stored XOR-swizzled so column-of-W float4 reads spread across banks.
#define WT_IDX(c, k) ((c) * 96 + (((k) ^ (((c) & 7) << 2))))

// ================= CSR build =================

__global__ void k_zero_i(int* __restrict__ p, int n) {
    int i = blockIdx.x * blockDim.x + threadIdx.x;
    if (i < n) p[i] = 0;
}

__global__ void k_hist(const int* __restrict__ dst, int* __restrict__ hist, int E) {
    int e = blockIdx.x * blockDim.x + threadIdx.x;
    if (e < E) atomicAdd(&hist[dst[e]], 1);
}

__global__ void k_dinv(const int* __restrict__ hist, float* __restrict__ dinv, int N) {
    int i = blockIdx.x * blockDim.x + threadIdx.x;
    if (i < N) dinv[i] = rsqrtf((float)hist[i] + 1.0f);  // +1 self-loop
}

__global__ __launch_bounds__(SCAN_B) void k_scan1(const int* __restrict__ hist,
                                                  int* __restrict__ incl,
                                                  int* __restrict__ bsum, int N) {
    __shared__ int s[SCAN_B];
    int i = blockIdx.x * SCAN_B + threadIdx.x;
    int v = (i < N) ? hist[i] : 0;
    s[threadIdx.x] = v;
    __syncthreads();
    for (int off = 1; off < SCAN_B; off <<= 1) {
        int add = (threadIdx.x >= off) ? s[threadIdx.x - off] : 0;
        __syncthreads();
        s[threadIdx.x] += add;
        __syncthreads();
    }
    if (i < N) incl[i] = s[threadIdx.x];
    if (threadIdx.x == SCAN_B - 1) bsum[blockIdx.x] = s[SCAN_B - 1];
}

__global__ __launch_bounds__(SCAN_B) void k_scan2(int* __restrict__ bsum, int nb) {
    __shared__ int s[SCAN_B];
    int v = (threadIdx.x < nb) ? bsum[threadIdx.x] : 0;
    s[threadIdx.x] = v;
    __syncthreads();
    for (int off = 1; off < SCAN_B; off <<= 1) {
        int add = (threadIdx.x >= off) ? s[threadIdx.x - off] : 0;
        __syncthreads();
        s[threadIdx.x] += add;
        __syncthreads();
    }
    if (threadIdx.x < nb) bsum[threadIdx.x] = s[threadIdx.x] - v;  // exclusive
}

__global__ void k_scan3(const int* __restrict__ incl, const int* __restrict__ hist,
                        const int* __restrict__ bsum, int* __restrict__ row_ptr,
                        int* __restrict__ cursor, int N, int E) {
    int i = blockIdx.x * blockDim.x + threadIdx.x;
    if (i < N) {
        int start = incl[i] - hist[i] + bsum[i / SCAN_B];
        row_ptr[i] = start;
        cursor[i] = start;
    }
    if (i == 0) row_ptr[N] = E;
}

__global__ void k_place(const int* __restrict__ src, const int* __restrict__ dst,
                        int* __restrict__ cursor, int* __restrict__ csr_src, int E) {
    int e = blockIdx.x * blockDim.x + threadIdx.x;
    if (e >= E) return;
    int pos = atomicAdd(&cursor[dst[e]], 1);
    csr_src[pos] = src[e];
}

// ================= dense =================
// COUT_SCALED=true: H' = dinv[row] * ((relu?)(X) @ W), written chunk-major
// [8][N][sOut] with pad slots (>=CW) zeroed. CHIN_CHUNK: input chunk-major
// [8][N][sIn] (only first CW slots read). Otherwise row-major [N][96].

template <bool RELU_IN, bool CHIN_CHUNK, bool COUT_SCALED>
__global__ __launch_bounds__(256) void k_dense(const float* __restrict__ X,
                                               const float* __restrict__ W,
                                               float* __restrict__ H,
                                               const float* __restrict__ dinv,
                                               int N, int sIn, int sOut) {
    __shared__ float Wt[96 * 96];
    __shared__ float XsOs[64][100];
    int t = threadIdx.x;
    const size_t NCin = (size_t)N * sIn;
    const size_t NCout = (size_t)N * sOut;

    // vectorized W staging: float4 global loads, 4 scalar ds_writes each
    for (int i4 = t * 4; i4 < F * F; i4 += 256 * 4) {
        float4 w = *reinterpret_cast<const float4*>(W + i4);
        int k = i4 / F, c = i4 % F;
        Wt[WT_IDX(c + 0, k)] = w.x;
        Wt[WT_IDX(c + 1, k)] = w.y;
        Wt[WT_IDX(c + 2, k)] = w.z;
        Wt[WT_IDX(c + 3, k)] = w.w;
    }
    int row0 = blockIdx.x * 64;

    // ---- stage input tile ----
    if (CHIN_CHUNK) {
        for (int q = t; q < 1536; q += 256) {
            int f = q / 192, rem = q % 192;
            int node = rem / 3, o = (rem % 3) * 4;
            int gr = row0 + node;
            float4 v = make_float4(0.f, 0.f, 0.f, 0.f);
            if (gr < N) {
                v = *reinterpret_cast<const float4*>(X + (size_t)f * NCin + (size_t)gr * sIn + o);
                if (RELU_IN) {
                    v.x = fmaxf(v.x, 0.f); v.y = fmaxf(v.y, 0.f);
                    v.z = fmaxf(v.z, 0.f); v.w = fmaxf(v.w, 0.f);
                }
            }
            *reinterpret_cast<float4*>(&XsOs[node][f * CW + o]) = v;
        }
    } else {
        for (int q = t; q < 1536; q += 256) {
            int node = q / 24, o = (q % 24) * 4;
            int gr = row0 + node;
            float4 v = make_float4(0.f, 0.f, 0.f, 0.f);
            if (gr < N) {
                v = *reinterpret_cast<const float4*>(X + (size_t)gr * F + o);
                if (RELU_IN) {
                    v.x = fmaxf(v.x, 0.f); v.y = fmaxf(v.y, 0.f);
                    v.z = fmaxf(v.z, 0.f); v.w = fmaxf(v.w, 0.f);
                }
            }
            *reinterpret_cast<float4*>(&XsOs[node][o]) = v;
        }
    }
    __syncthreads();

    // ---- compute ----
    int c2 = t & 31;
    int rg = t >> 5;
    float acc[8][3];
#pragma unroll
    for (int j = 0; j < 8; ++j) { acc[j][0] = 0.f; acc[j][1] = 0.f; acc[j][2] = 0.f; }

    for (int k4 = 0; k4 < F; k4 += 4) {
        float4 w0 = *reinterpret_cast<const float4*>(&Wt[WT_IDX(c2, k4)]);
        float4 w1 = *reinterpret_cast<const float4*>(&Wt[WT_IDX(c2 + 32, k4)]);
        float4 w2 = *reinterpret_cast<const float4*>(&Wt[WT_IDX(c2 + 64, k4)]);
#pragma unroll
        for (int j = 0; j < 8; ++j) {
            float4 xv = *reinterpret_cast<const float4*>(&XsOs[rg + 8 * j][k4]);
            acc[j][0] = fmaf(xv.x, w0.x, acc[j][0]);
            acc[j][1] = fmaf(xv.x, w1.x, acc[j][1]);
            acc[j][2] = fmaf(xv.x, w2.x, acc[j][2]);
            acc[j][0] = fmaf(xv.y, w0.y, acc[j][0]);
            acc[j][1] = fmaf(xv.y, w1.y, acc[j][1]);
            acc[j][2] = fmaf(xv.y, w2.y, acc[j][2]);
            acc[j][0] = fmaf(xv.z, w0.z, acc[j][0]);
            acc[j][1] = fmaf(xv.z, w1.z, acc[j][1]);
            acc[j][2] = fmaf(xv.z, w2.z, acc[j][2]);
            acc[j][0] = fmaf(xv.w, w0.w, acc[j][0]);
            acc[j][1] = fmaf(xv.w, w1.w, acc[j][1]);
            acc[j][2] = fmaf(xv.w, w2.w, acc[j][2]);
        }
    }
    __syncthreads();  // all k-loop reads done before overwriting XsOs

    // ---- stage output tile to LDS (scaled by dinv if COUT_SCALED) ----
#pragma unroll
    for (int j = 0; j < 8; ++j) {
        float dd = 1.f;
        if (COUT_SCALED) {
            int gr = row0 + rg + 8 * j;
            dd = (gr < N) ? dinv[gr] : 0.f;
        }
        XsOs[rg + 8 * j][c2]      = acc[j][0] * dd;
        XsOs[rg + 8 * j][c2 + 32] = acc[j][1] * dd;
        XsOs[rg + 8 * j][c2 + 64] = acc[j][2] * dd;
    }
    __syncthreads();

    // ---- coalesced store ----
    if (COUT_SCALED) {
        int nfq = sOut >> 2;  // 3 or 4 float4 per (chunk,node)
        for (int q = t; q < 512 * nfq; q += 256) {
            int ch = q / (64 * nfq);
            int rem = q % (64 * nfq);
            int node = rem / nfq;
            int o4 = (rem % nfq) * 4;
            int gr = row0 + node;
            if (gr < N) {
                float4 v = make_float4(0.f, 0.f, 0.f, 0.f);
                if (o4 < CW) v = *reinterpret_cast<const float4*>(&XsOs[node][ch * CW + o4]);
                *reinterpret_cast<float4*>(H + (size_t)ch * NCout + (size_t)gr * sOut + o4) = v;
            }
        }
    } else {
        for (int q = t; q < 1536; q += 256) {
            int node = q / 24, o = (q % 24) * 4;
            int gr = row0 + node;
            if (gr < N) {
                *reinterpret_cast<float4*>(H + (size_t)gr * F + o) =
                    *reinterpret_cast<const float4*>(&XsOs[node][o]);
            }
        }
    }
}

// ================= gather v3 (chunk x XCD, float4 slots, 4-chain MLP) =======
// Requires sA == 16 (padded chunk rows). Block = 64 nodes; slot = 4 lanes x
// float4 (one 64-B line per edge-visit). Nodes rank-sorted by degree so each
// wave's 16 slots have similar degree. CSR range staged in LDS. Inner loop
// unrolled x4 with 4 independent accumulator chains (4 outstanding loads).
// O[d] = dinv[d] * (sum_e H'[src_e] + H'[d]) + b   (H' prescaled by dinv)

template <bool OUT_ROW>
__global__ __launch_bounds__(256) void k_gather16(const float* __restrict__ Hc,
                                                  const int* __restrict__ csr_src,
                                                  const int* __restrict__ row_ptr,
                                                  const float* __restrict__ dinv,
                                                  const float* __restrict__ bias,
                                                  float* __restrict__ O,
                                                  int N, int sB) {
    __shared__ int eidx[EWIN];
    __shared__ int sdeg[64];
    __shared__ int ord[64];
    const int tid = threadIdx.x;
    const int chunk = blockIdx.x & (CHUNKS - 1);
    const int nb0 = (blockIdx.x >> 3) * 64;
    const float* Hk = Hc + (size_t)chunk * (size_t)N * 16;

    const int nEnd = min(nb0 + 64, N);
    const int nloc = nEnd - nb0;

    // ---- rank-sort the block's 64 nodes by degree (ascending) ----
    if (tid < 64) {
        int nd = nb0 + tid;
        sdeg[tid] = (nd < N) ? (row_ptr[nd + 1] - row_ptr[nd]) : -1;
    }
    __syncthreads();
    if (tid < 64) {
        int d = sdeg[tid];
        int r = 0;
#pragma unroll 8
        for (int j = 0; j < 64; ++j) {
            int dj = sdeg[j];
            r += (dj < d) || (dj == d && j < tid);
        }
        ord[r] = tid;
    }
    __syncthreads();

    const int slot = tid >> 2;        // 0..63 (wave = 16 consecutive ranks)
    const int fl = (tid & 3) * 4;     // feature base within padded row
    int node = -1, s0 = 0, s1 = 0;
    {
        int on = ord[slot];
        int nd = nb0 + on;
        if (on < nloc && nd < N) { node = nd; s0 = row_ptr[nd]; s1 = row_ptr[nd + 1]; }
    }

    float4 a0 = make_float4(0.f, 0.f, 0.f, 0.f);
    float4 a1 = make_float4(0.f, 0.f, 0.f, 0.f);
    float4 a2 = make_float4(0.f, 0.f, 0.f, 0.f);
    float4 a3 = make_float4(0.f, 0.f, 0.f, 0.f);
    const int B0 = row_ptr[nb0];
    const int B1 = row_ptr[nEnd];
    for (int wb = B0; wb < B1; wb += EWIN) {
        int wcnt = min(EWIN, B1 - wb);
        __syncthreads();  // previous window fully consumed
        for (int q = tid; q < wcnt; q += 256)
            eidx[q] = __builtin_nontemporal_load(csr_src + wb + q);
        __syncthreads();
        int e  = max(s0, wb) - wb;
        int e1 = min(s1, wb + wcnt) - wb;
        for (; e + 3 < e1; e += 4) {
            int i0 = eidx[e];
            int i1 = eidx[e + 1];
            int i2 = eidx[e + 2];
            int i3 = eidx[e + 3];
            float4 v0 = *reinterpret_cast<const float4*>(Hk + (size_t)i0 * 16 + fl);
            float4 v1 = *reinterpret_cast<const float4*>(Hk + (size_t)i1 * 16 + fl);
            float4 v2 = *reinterpret_cast<const float4*>(Hk + (size_t)i2 * 16 + fl);
            float4 v3 = *reinterpret_cast<const float4*>(Hk + (size_t)i3 * 16 + fl);
            a0.x += v0.x; a0.y += v0.y; a0.z += v0.z; a0.w += v0.w;
            a1.x += v1.x; a1.y += v1.y; a1.z += v1.z; a1.w += v1.w;
            a2.x += v2.x; a2.y += v2.y; a2.z += v2.z; a2.w += v2.w;
            a3.x += v3.x; a3.y += v3.y; a3.z += v3.z; a3.w += v3.w;
        }
        for (; e < e1; ++e) {
            int i0 = eidx[e];
            float4 v0 = *reinterpret_cast<const float4*>(Hk + (size_t)i0 * 16 + fl);
            a0.x += v0.x; a0.y += v0.y; a0.z += v0.z; a0.w += v0.w;
        }
    }
    if (node < 0) return;

    float di = dinv[node];
    float4 self = *reinterpret_cast<const float4*>(Hk + (size_t)node * 16 + fl);
    float4 b4 = make_float4(0.f, 0.f, 0.f, 0.f);
    if (fl < CW) b4 = *reinterpret_cast<const float4*>(bias + chunk * CW + fl);
    float4 r;
    r.x = fmaf(a0.x + a1.x + a2.x + a3.x + self.x, di, b4.x);
    r.y = fmaf(a0.y + a1.y + a2.y + a3.y + self.y, di, b4.y);
    r.z = fmaf(a0.z + a1.z + a2.z + a3.z + self.z, di, b4.z);
    r.w = fmaf(a0.w + a1.w + a2.w + a3.w + self.w, di, b4.w);

    if (OUT_ROW) {
        if (fl < CW)
            *reinterpret_cast<float4*>(O + (size_t)node * F + chunk * CW + fl) = r;
    } else {
        // sB == 16: full padded row written (pads garbage, never read)
        *reinterpret_cast<float4*>(O + (size_t)chunk * (size_t)N * 16 + (size_t)node * 16 + fl) = r;
    }
}

// ================= gather legacy (stride-12-capable, slot-per-node) =========

template <bool OUT_ROW>
__global__ __launch_bounds__(256) void k_gather(const float* __restrict__ Hc,
                                                const int* __restrict__ csr_src,
                                                const int* __restrict__ row_ptr,
                                                const float* __restrict__ dinv,
                                                const float* __restrict__ bias,
                                                float* __restrict__ O,
                                                int N, int sA, int sB) {
    __shared__ int eidx[EWIN];
    const int tid = threadIdx.x;
    const int chunk = blockIdx.x & (CHUNKS - 1);
    const int nb0 = (blockIdx.x >> 3) * 16;
    const int slot = tid >> 4;
    const int f = tid & 15;
    const int node = nb0 + slot;
    const float* Hk = Hc + (size_t)chunk * (size_t)N * sA;

    float bf = (f < CW) ? bias[chunk * CW + f] : 0.f;
    const int nEnd = min(nb0 + 16, N);
    const int B0 = row_ptr[nb0];
    const int B1 = row_ptr[nEnd];
    int s0 = 0, s1 = 0;
    if (node < N) { s0 = row_ptr[node]; s1 = row_ptr[node + 1]; }

    float acc0 = 0.f, acc1 = 0.f;
    for (int wb = B0; wb < B1; wb += EWIN) {
        int wcnt = min(EWIN, B1 - wb);
        __syncthreads();
        for (int q = tid; q < wcnt; q += 256)
            eidx[q] = __builtin_nontemporal_load(csr_src + wb + q);
        __syncthreads();
        int e  = max(s0, wb);
        int e1 = min(s1, wb + wcnt);
        for (; e + 1 < e1; e += 2) {
            int i0 = eidx[e - wb];
            int i1 = eidx[e - wb + 1];
            acc0 += Hk[(size_t)i0 * sA + f];
            acc1 += Hk[(size_t)i1 * sA + f];
        }
        if (e < e1) acc0 += Hk[(size_t)eidx[e - wb] * sA + f];
    }
    if (node >= N) return;

    float di = dinv[node];
    float self = Hk[(size_t)node * sA + f];
    float r = fmaf(acc0 + acc1 + self, di, bf);

    if (OUT_ROW) {
        if (f < CW) O[(size_t)node * F + chunk * CW + f] = r;
    } else if (sB == 16) {
        O[(size_t)chunk * (size_t)N * 16 + (size_t)node * 16 + f] = r;
    } else {
        if (f < CW) O[(size_t)chunk * (size_t)N * CW + (size_t)node * CW + f] = r;
    }
}

// ================= fallback (atomic-scatter path, row-major) =================

__global__ void k_init_deg(float* __restrict__ deg, int N) {
    int i = blockIdx.x * blockDim.x + threadIdx.x;
    if (i < N) deg[i] = 1.0f;
}
__global__ void k_count(const int* __restrict__ dst, float* __restrict__ deg, int E) {
    int e = blockIdx.x * blockDim.x + threadIdx.x;
    if (e < E) atomicAdd(&deg[dst[e]], 1.0f);
}
__global__ void k_rsqrt(float* __restrict__ deg, int N) {
    int i = blockIdx.x * blockDim.x + threadIdx.x;
    if (i < N) deg[i] = rsqrtf(deg[i]);
}
__global__ void k_init_out(const float* __restrict__ H, const float* __restrict__ dinv,
                           const float* __restrict__ b, float* __restrict__ O, int N) {
    int idx = blockIdx.x * blockDim.x + threadIdx.x;
    if (idx >= N * F) return;
    int i = idx / F, f = idx % F;
    float di = dinv[i];
    O[idx] = fmaf(H[idx], di * di, b[f]);
}
__global__ __launch_bounds__(256) void k_scatter(const float* __restrict__ H,
                                                 const int* __restrict__ src,
                                                 const int* __restrict__ dst,
                                                 const float* __restrict__ dinv,
                                                 float* __restrict__ O, int E) {
    int t = blockIdx.x * 256 + threadIdx.x;
    int e = t >> 5;
    if (e >= E) return;
    int lf = t & 31;
    int s = src[e], d = dst[e];
    float nrm = dinv[s] * dinv[d];
    const float* hs = H + (size_t)s * F;
    float* od = O + (size_t)d * F;
#pragma unroll
    for (int j = 0; j < 3; ++j) atomicAdd(&od[lf + 32 * j], hs[lf + 32 * j] * nrm);
}

// ================= launch =================

static inline size_t align64f(size_t x) { return (x + 63) & ~(size_t)63; }

extern "C" void kernel_launch(void* const* d_in, const int* in_sizes, int n_in,
                              void* d_out, int out_size, void* d_ws, size_t ws_size,
                              hipStream_t stream) {
    const float* x  = (const float*)d_in[0];
    const float* W1 = (const float*)d_in[1];
    const float* b1 = (const float*)d_in[2];
    const float* W2 = (const float*)d_in[3];
    const float* b2 = (const float*)d_in[4];
    const float* W3 = (const float*)d_in[5];
    const float* b3 = (const float*)d_in[6];
    const int*   ei = (const int*)d_in[7];

    const int N = in_sizes[0] / F;
    const int E = in_sizes[7] / 2;
    const int* src = ei;
    const int* dst = ei + E;
    const size_t NF = (size_t)N * F;

    const int thr = 256;
    dim3 blk(thr);
    int gN  = (N + thr - 1) / thr;
    int gE  = (E + thr - 1) / thr;
    int gDen = (N + 63) / 64;
    int gGat16 = CHUNKS * ((N + 63) / 64);
    int gGatLeg = CHUNKS * ((N + 15) / 16);
    int nScanB = (N + SCAN_B - 1) / SCAN_B;

    // ---- workspace layout (units: floats/ints) ----
    size_t o_rp  = align64f(N);                     // dinv in [0,N)
    size_t o_csr = o_rp + align64f((size_t)N + 1);
    size_t o_A   = o_csr + align64f((size_t)E + 4);
    size_t szA16 = (size_t)CHUNKS * N * 16 + 64;
    size_t szA12 = (size_t)CHUNKS * N * 12 + 64;
    size_t t1616 = (o_A + align64f(szA16) + szA16) * 4;
    size_t t1612 = (o_A + align64f(szA16) + szA12) * 4;
    size_t t1212 = (o_A + align64f(szA12) + szA12) * 4;

    int sA = 16, sB = 16;
    size_t o_B = 0;
    bool csr_ok = (nScanB <= SCAN_B);
    bool fast16 = false;
    if (ws_size >= t1616)      { sA = 16; sB = 16; o_B = o_A + align64f(szA16); fast16 = true; }
    else if (ws_size >= t1612) { sA = 16; sB = 12; o_B = o_A + align64f(szA16); }
    else if (ws_size >= t1212) { sA = 12; sB = 12; o_B = o_A + align64f(szA12); }
    else csr_ok = false;

    float* wsf     = (float*)d_ws;
    float* dinv    = wsf;
    int*   row_ptr = (int*)(wsf + o_rp);
    int*   csr_src = (int*)(wsf + o_csr);
    float* A       = wsf + (csr_ok ? o_A : 0);
    float* B       = wsf + (csr_ok ? o_B : 0);
    int* hist   = (int*)A;      // temps (dead before A/B use)
    int* incl   = hist + N;
    int* cursor = (int*)B;
    int* bsum   = cursor + N;

    float* out = (float*)d_out;

    if (csr_ok) {
        // ---- CSR build (once; reused by all 3 layers) ----
        k_zero_i<<<gN, blk, 0, stream>>>(hist, N);
        k_hist<<<gE, blk, 0, stream>>>(dst, hist, E);
        k_scan1<<<nScanB, dim3(SCAN_B), 0, stream>>>(hist, incl, bsum, N);
        k_scan2<<<1, dim3(SCAN_B), 0, stream>>>(bsum, nScanB);
        k_scan3<<<gN, blk, 0, stream>>>(incl, hist, bsum, row_ptr, cursor, N, E);
        k_dinv<<<gN, blk, 0, stream>>>(hist, dinv, N);   // before A is overwritten
        k_place<<<gE, blk, 0, stream>>>(src, dst, cursor, csr_src, E);

        if (fast16) {
            // ---- layer 1 ----
            k_dense<false, false, true><<<gDen, blk, 0, stream>>>(x, W1, A, dinv, N, F, 16);
            k_gather16<false><<<gGat16, blk, 0, stream>>>(A, csr_src, row_ptr, dinv, b1, B, N, 16);
            // ---- layer 2 ----
            k_dense<true, true, true><<<gDen, blk, 0, stream>>>(B, W2, A, dinv, N, 16, 16);
            k_gather16<false><<<gGat16, blk, 0, stream>>>(A, csr_src, row_ptr, dinv, b2, B, N, 16);
            // ---- layer 3 ----
            k_dense<true, true, true><<<gDen, blk, 0, stream>>>(B, W3, A, dinv, N, 16, 16);
            k_gather16<true><<<gGat16, blk, 0, stream>>>(A, csr_src, row_ptr, dinv, b3, out, N, 0);
        } else {
            // ---- layer 1 ----
            k_dense<false, false, true><<<gDen, blk, 0, stream>>>(x, W1, A, dinv, N, F, sA);
            k_gather<false><<<gGatLeg, blk, 0, stream>>>(A, csr_src, row_ptr, dinv, b1, B, N, sA, sB);
            // ---- layer 2 ----
            k_dense<true, true, true><<<gDen, blk, 0, stream>>>(B, W2, A, dinv, N, sB, sA);
            k_gather<false><<<gGatLeg, blk, 0, stream>>>(A, csr_src, row_ptr, dinv, b2, B, N, sA, sB);
            // ---- layer 3 ----
            k_dense<true, true, true><<<gDen, blk, 0, stream>>>(B, W3, A, dinv, N, sB, sA);
            k_gather<true><<<gGatLeg, blk, 0, stream>>>(A, csr_src, row_ptr, dinv, b3, out, N, sA, 0);
        }
    } else {
        // ---- fallback: atomic-scatter path ----
        float* fdinv = (float*)d_ws;
        float* fA = fdinv + N;
        float* fB = fA + NF;
        int gNF = (int)((NF + thr - 1) / thr);
        int gSc = (int)(((size_t)E * 32 + thr - 1) / thr);
        k_init_deg<<<gN, blk, 0, stream>>>(fdinv, N);
        k_count<<<gE, blk, 0, stream>>>(dst, fdinv, E);
        k_rsqrt<<<gN, blk, 0, stream>>>(fdinv, N);
        k_dense<false, false, false><<<gDen, blk, 0, stream>>>(x, W1, fA, fdinv, N, F, F);
        k_init_out<<<gNF, blk, 0, stream>>>(fA, fdinv, b1, fB, N);
        k_scatter<<<gSc, blk, 0, stream>>>(fA, src, dst, fdinv, fB, E);
        k_dense<true, false, false><<<gDen, blk, 0, stream>>>(fB, W2, fA, fdinv, N, F, F);
        k_init_out<<<gNF, blk, 0, stream>>>(fA, fdinv, b2, out, N);
        k_scatter<<<gSc, blk, 0, stream>>>(fA, src, dst, fdinv, out, E);
        k_dense<true, false, false><<<gDen, blk, 0, stream>>>(out, W3, fA, fdinv, N, F, F);
        k_init_out<<<gNF, blk, 0, stream>>>(fA, fdinv, b3, fB, N);
        k_scatter<<<gSc, blk, 0, stream>>>(fA, src, dst, fdinv, fB, E);
        hipMemcpyAsync(out, fB, NF * sizeof(float), hipMemcpyDeviceToDevice, stream);
    }
}